// Round 3
// baseline (66.865 us; speedup 1.0000x reference)
//
#include <hip/hip_runtime.h>

#define B_ 64
#define H_ 384
#define W_ 384
#define C_ 3

__global__ __launch_bounds__(256) void bilerp_kernel(
    const float* __restrict__ images,
    const float* __restrict__ theta,
    float* __restrict__ out)
{
    const int total = B_ * H_ * W_;
    int idx = blockIdx.x * blockDim.x + threadIdx.x;
    if (idx >= total) return;

    int j = idx % W_;
    int t = idx / W_;
    int i = t % H_;
    int b = t / H_;

    // numpy linspace(-1,1,N,dtype=f32): computed in f64 (k*step - 1), endpoint
    // forced to exactly 1.0, THEN cast to f32. Replicate bit-exactly.
    const double STEP = 2.0 / 383.0;
    float xs = (j == W_ - 1) ? 1.0f : (float)((double)j * STEP - 1.0);
    float ys = (i == H_ - 1) ? 1.0f : (float)((double)i * STEP - 1.0);

    const float* th = theta + b * 6;
    // numpy einsum f32 C-loop: sequential accumulation, each mul/add rounded,
    // no FMA contraction. ((th0*xs) + (th1*ys)) + th2
    float t0 = __fadd_rn(__fadd_rn(__fmul_rn(th[0], xs), __fmul_rn(th[1], ys)), th[2]);
    float t1 = __fadd_rn(__fadd_rn(__fmul_rn(th[3], xs), __fmul_rn(th[4], ys)), th[5]);

    float x = __fmul_rn(__fadd_rn(t0, 1.0f), (float)(W_ * 0.5));
    float y = __fmul_rn(__fadd_rn(t1, 1.0f), (float)(H_ * 0.5));

    float fx = floorf(x);
    float fy = floorf(y);
    int x0 = min(max((int)fx, 0), W_ - 1);
    int x1 = min(max((int)fx + 1, 0), W_ - 1);
    int y0 = min(max((int)fy, 0), H_ - 1);
    int y1 = min(max((int)fy + 1, 0), H_ - 1);

    float xc = fminf(fmaxf(x, 0.0f), (float)(W_ - 1));
    float yc = fminf(fmaxf(y, 0.0f), (float)(H_ - 1));

    float x0f = (float)x0, x1f = (float)x1;
    float y0f = (float)y0, y1f = (float)y1;

    // per-op rounded f32, no contraction
    float wa = __fmul_rn(__fsub_rn(x1f, xc), __fsub_rn(y1f, yc));
    float wb = __fmul_rn(__fsub_rn(x1f, xc), __fsub_rn(yc, y0f));
    float wc = __fmul_rn(__fsub_rn(xc, x0f), __fsub_rn(y1f, yc));
    float wd = __fmul_rn(__fsub_rn(xc, x0f), __fsub_rn(yc, y0f));

    const float* img = images + (size_t)b * (H_ * W_ * C_);
    const float* pa = img + (y0 * W_ + x0) * C_;
    const float* pb = img + (y1 * W_ + x0) * C_;
    const float* pc = img + (y0 * W_ + x1) * C_;
    const float* pd = img + (y1 * W_ + x1) * C_;

    float* o = out + (size_t)idx * C_;
#pragma unroll
    for (int c = 0; c < C_; ++c) {
        // ((wa*Ia + wb*Ib) + wc*Ic) + wd*Id, each op f32-rounded
        float v = __fadd_rn(
                    __fadd_rn(
                      __fadd_rn(__fmul_rn(wa, pa[c]), __fmul_rn(wb, pb[c])),
                      __fmul_rn(wc, pc[c])),
                    __fmul_rn(wd, pd[c]));
        o[c] = v;
    }
}

extern "C" void kernel_launch(void* const* d_in, const int* in_sizes, int n_in,
                              void* d_out, int out_size, void* d_ws, size_t ws_size,
                              hipStream_t stream) {
    const float* images = (const float*)d_in[0];
    const float* theta  = (const float*)d_in[1];
    float* out = (float*)d_out;

    const int total = B_ * H_ * W_;
    const int block = 256;
    const int grid = (total + block - 1) / block;
    bilerp_kernel<<<grid, block, 0, stream>>>(images, theta, out);
}